// Round 4
// baseline (236.861 us; speedup 1.0000x reference)
//
#include <hip/hip_runtime.h>

#define NMOL 128
#define ZMAX 90
#define TBL (2 * 2 * ZMAX * ZMAX)   // 32400 floats = 129.6 KB
#define BLOCK_E 1024                 // 16 waves/block, 1 block/CU (LDS-capped)
#define GRID_E 256
#define BLOCK_P 256

typedef float  fx4 __attribute__((ext_vector_type(4)));
typedef int    ix4 __attribute__((ext_vector_type(4)));

__device__ __forceinline__ float fast_exp2(float x) {
#if __has_builtin(__builtin_amdgcn_exp2f)
    return __builtin_amdgcn_exp2f(x);
#else
    return exp2f(x);
#endif
}
__device__ __forceinline__ float fast_log2(float x) {
#if __has_builtin(__builtin_amdgcn_logf)
    return __builtin_amdgcn_logf(x);   // v_log_f32 computes log2(x)
#else
    return log2f(x);
#endif
}
__device__ __forceinline__ float fast_rcp(float x) {
#if __has_builtin(__builtin_amdgcn_rcpf)
    return __builtin_amdgcn_rcpf(x);
#else
    return 1.0f / x;
#endif
}

// Pack per-atom data into one 16B record: {q, ns, Z | is_film<<16, mol}.
// Cuts per-edge gathers 9 -> 2. Also zero-inits d_out (harness re-poisons
// it with 0xAA before every timed launch).
__global__ void pack_atoms_kernel(const float* __restrict__ q,
                                  const int* __restrict__ Z,
                                  const float* __restrict__ ns,
                                  const int* __restrict__ idx_m,
                                  const int* __restrict__ is_film,
                                  float4* __restrict__ atoms,
                                  float* __restrict__ out, int nA) {
    int t = blockIdx.x * BLOCK_P + threadIdx.x;
    if (blockIdx.x == 0 && threadIdx.x < NMOL) out[threadIdx.x] = 0.0f;
    if (t < nA) {
        float4 a;
        a.x = q[t];
        a.y = ns[t];
        a.z = __int_as_float(Z[t] | (is_film[t] << 16));
        a.w = __int_as_float(idx_m[t]);
        atoms[t] = a;
    }
}

// Per-edge tail math once ai/aj/r0 are in registers.
__device__ __forceinline__ float pot_from(const float4& ai, const float4& aj,
                                          float r0, float d2) {
    constexpr float LOG2_CUT = 2.321928094887362f; // log2(5.0)
    const float qij = fabsf(ai.x * aj.x);
    const float n = fmaf(0.5f, aj.y, ai.y);              // ns_i + ns_j/2
    const float B = qij * fast_exp2((n - 1.0f) * fast_log2(r0)) * fast_rcp(n);
    const float dpow = fast_exp2(-0.5f * n * fast_log2(d2)); // d^-n without sqrt
    const float cpow = fast_exp2(-n * LOG2_CUT);             // 5^-n
    return (d2 <= 25.0f) ? B * (dpow - cpow) : 0.0f;
}

__device__ __forceinline__ int tbl_idx(const float4& ai, const float4& aj) {
    int zi = __float_as_int(ai.z);
    int zj = __float_as_int(aj.z);
    const int fi = zi >> 16, fj = zj >> 16;
    zi &= 0xFFFF; zj &= 0xFFFF;
    return ((fi * 2 + fj) * ZMAX + zi) * ZMAX + zj;
}

// Edge kernel: r0_table lives in LDS (kills the dependent 2nd L2 hop and 25%
// of random L2 requests). 4 edges/thread with ALL 8 atom gathers issued
// before any use; __launch_bounds__(1024,4) gives a 128-VGPR budget so the
// compiler keeps them in flight (round-2 build collapsed to 28 VGPRs).
__global__ void __launch_bounds__(BLOCK_E, 4)
edge_kernel(const float4* __restrict__ atoms,
            const float* __restrict__ r0_table,
            const fx4* __restrict__ Rij4,
            const ix4* __restrict__ idx_i4,
            const ix4* __restrict__ idx_j4,
            float* __restrict__ out, int nE) {
    constexpr float HALF_KE = 7.1998f; // 0.5 * 14.3996

    __shared__ float r0_lds[TBL];
    __shared__ float bins[NMOL];

    // Stage the full table (32400 floats = 8100 float4, exactly divisible).
    {
        const fx4* src = (const fx4*)r0_table;
        fx4* dst = (fx4*)r0_lds;
        for (int t = threadIdx.x; t < TBL / 4; t += BLOCK_E) dst[t] = src[t];
    }
    for (int t = threadIdx.x; t < NMOL; t += BLOCK_E) bins[t] = 0.0f;
    __syncthreads();

    const int nE4 = nE >> 2;
    const int stride = gridDim.x * BLOCK_E;
    for (int t = blockIdx.x * BLOCK_E + threadIdx.x; t < nE4; t += stride) {
        // Streaming loads (nontemporal: keep L1/L2 for atom gathers).
        const ix4 ii = __builtin_nontemporal_load(&idx_i4[t]);
        const ix4 jj = __builtin_nontemporal_load(&idx_j4[t]);
        const fx4 ra = __builtin_nontemporal_load(&Rij4[3 * t + 0]);
        const fx4 rb = __builtin_nontemporal_load(&Rij4[3 * t + 1]);
        const fx4 rc = __builtin_nontemporal_load(&Rij4[3 * t + 2]);

        // Issue all 8 atom gathers back-to-back.
        const float4 a0 = atoms[ii.x];
        const float4 a1 = atoms[ii.y];
        const float4 a2 = atoms[ii.z];
        const float4 a3 = atoms[ii.w];
        const float4 b0 = atoms[jj.x];
        const float4 b1 = atoms[jj.y];
        const float4 b2 = atoms[jj.z];
        const float4 b3 = atoms[jj.w];

        const float d20 = fmaf(ra.x, ra.x, fmaf(ra.y, ra.y, ra.z * ra.z));
        const float d21 = fmaf(ra.w, ra.w, fmaf(rb.x, rb.x, rb.y * rb.y));
        const float d22 = fmaf(rb.z, rb.z, fmaf(rb.w, rb.w, rc.x * rc.x));
        const float d23 = fmaf(rc.y, rc.y, fmaf(rc.z, rc.z, rc.w * rc.w));

        // Table lookups from LDS (separate pipe, no L2 request).
        const float r00 = r0_lds[tbl_idx(a0, b0)];
        const float r01 = r0_lds[tbl_idx(a1, b1)];
        const float r02 = r0_lds[tbl_idx(a2, b2)];
        const float r03 = r0_lds[tbl_idx(a3, b3)];

        const float p0 = pot_from(a0, b0, r00, d20);
        const float p1 = pot_from(a1, b1, r01, d21);
        const float p2 = pot_from(a2, b2, r02, d22);
        const float p3 = pot_from(a3, b3, r03, d23);

        if (p0 != 0.0f) atomicAdd(&bins[__float_as_int(a0.w)], p0);
        if (p1 != 0.0f) atomicAdd(&bins[__float_as_int(a1.w)], p1);
        if (p2 != 0.0f) atomicAdd(&bins[__float_as_int(a2.w)], p2);
        if (p3 != 0.0f) atomicAdd(&bins[__float_as_int(a3.w)], p3);
    }

    // Scalar tail for nE % 4 (empty for the canonical 6.4M edges).
    const int tail_start = nE4 << 2;
    const int* idx_i = (const int*)idx_i4;
    const int* idx_j = (const int*)idx_j4;
    const float* Rij = (const float*)Rij4;
    for (int e = tail_start + blockIdx.x * BLOCK_E + threadIdx.x; e < nE; e += stride) {
        const float4 ai = atoms[idx_i[e]];
        const float4 aj = atoms[idx_j[e]];
        const float x = Rij[3 * e + 0], y = Rij[3 * e + 1], z = Rij[3 * e + 2];
        const float d2 = fmaf(x, x, fmaf(y, y, z * z));
        const float p = pot_from(ai, aj, r0_lds[tbl_idx(ai, aj)], d2);
        if (p != 0.0f) atomicAdd(&bins[__float_as_int(ai.w)], p);
    }

    __syncthreads();
    for (int t = threadIdx.x; t < NMOL; t += BLOCK_E) {
        const float v = bins[t];
        if (v != 0.0f) atomicAdd(&out[t], v * HALF_KE);
    }
}

// Fallback when d_ws can't hold packed atoms: raw gathers (slower, correct).
__global__ void __launch_bounds__(BLOCK_P)
edge_kernel_raw(const float* __restrict__ q,
                const int* __restrict__ Z,
                const float* __restrict__ ns,
                const int* __restrict__ idx_m,
                const int* __restrict__ is_film,
                const float* __restrict__ r0_table,
                const float* __restrict__ Rij,
                const int* __restrict__ idx_i,
                const int* __restrict__ idx_j,
                float* __restrict__ out, int nE) {
    constexpr float HALF_KE = 7.1998f;
    constexpr float LOG2_CUT = 2.321928094887362f;

    __shared__ float bins[NMOL];
    for (int t = threadIdx.x; t < NMOL; t += BLOCK_P) bins[t] = 0.0f;
    __syncthreads();

    const int stride = gridDim.x * BLOCK_P;
    for (int e = blockIdx.x * BLOCK_P + threadIdx.x; e < nE; e += stride) {
        const int i = idx_i[e];
        const int j = idx_j[e];
        const float x = Rij[3 * e + 0], y = Rij[3 * e + 1], z = Rij[3 * e + 2];
        const float d2 = fmaf(x, x, fmaf(y, y, z * z));
        const float r0 = r0_table[((is_film[i] * 2 + is_film[j]) * ZMAX + Z[i]) * ZMAX + Z[j]];
        const float qij = fabsf(q[i] * q[j]);
        const float n = fmaf(0.5f, ns[j], ns[i]);
        const float B = qij * fast_exp2((n - 1.0f) * fast_log2(r0)) * fast_rcp(n);
        const float dpow = fast_exp2(-0.5f * n * fast_log2(d2));
        const float cpow = fast_exp2(-n * LOG2_CUT);
        if (d2 <= 25.0f) atomicAdd(&bins[idx_m[i]], B * (dpow - cpow));
    }

    __syncthreads();
    for (int t = threadIdx.x; t < NMOL; t += BLOCK_P) {
        const float v = bins[t];
        if (v != 0.0f) atomicAdd(&out[t], v * HALF_KE);
    }
}

__global__ void zero_out_kernel(float* __restrict__ out) {
    if (threadIdx.x < NMOL) out[threadIdx.x] = 0.0f;
}

extern "C" void kernel_launch(void* const* d_in, const int* in_sizes, int n_in,
                              void* d_out, int out_size, void* d_ws, size_t ws_size,
                              hipStream_t stream) {
    const float* q        = (const float*)d_in[0];
    const int*   Z        = (const int*)  d_in[1];
    const float* ns       = (const float*)d_in[2];
    const int*   idx_m    = (const int*)  d_in[3];
    const float* Rij      = (const float*)d_in[4];
    const int*   idx_i    = (const int*)  d_in[5];
    const int*   idx_j    = (const int*)  d_in[6];
    const int*   is_film  = (const int*)  d_in[7];
    const float* r0_table = (const float*)d_in[8];

    const int nA = in_sizes[0];
    const int nE = in_sizes[5];
    float* out = (float*)d_out;

    const size_t atoms_bytes = (size_t)nA * sizeof(float4);

    if (ws_size >= atoms_bytes) {
        float4* atoms = (float4*)d_ws;
        const int pack_grid = (nA + BLOCK_P - 1) / BLOCK_P;
        pack_atoms_kernel<<<pack_grid, BLOCK_P, 0, stream>>>(q, Z, ns, idx_m, is_film,
                                                             atoms, out, nA);
        edge_kernel<<<GRID_E, BLOCK_E, 0, stream>>>(atoms, r0_table,
                                                    (const fx4*)Rij,
                                                    (const ix4*)idx_i,
                                                    (const ix4*)idx_j,
                                                    out, nE);
    } else {
        zero_out_kernel<<<1, BLOCK_P, 0, stream>>>(out);
        edge_kernel_raw<<<2048, BLOCK_P, 0, stream>>>(q, Z, ns, idx_m, is_film, r0_table,
                                                      Rij, idx_i, idx_j, out, nE);
    }
}